// Round 1
// baseline (1019.152 us; speedup 1.0000x reference)
//
#include <hip/hip_runtime.h>
#include <stdint.h>

#define N 8192
#define D 256

typedef __attribute__((ext_vector_type(4))) float f32x4;
typedef __attribute__((ext_vector_type(8))) short bf16x8;

__device__ __forceinline__ unsigned short f2bf(float f) {
    unsigned u = __float_as_uint(f);
    u += 0x7fff + ((u >> 16) & 1);           // RNE
    return (unsigned short)(u >> 16);
}
__device__ __forceinline__ float leaky(float x) {
    return fmaxf(x, 0.f) + 0.2f * fminf(x, 0.f);
}
// CK-style block_sync_lds: LDS-ordering barrier that does NOT drain vmcnt,
// so register-destination global prefetches stay in flight across it.
__device__ __forceinline__ void sync_lds() {
    asm volatile("s_waitcnt lgkmcnt(0)\n\ts_barrier" ::: "memory");
}

// ---------------- K1: Wh = x @ W (fp32), also write WhT bf16 [D][N] ----------------
// v2: x-tile prefetched into registers across the barrier (HBM latency hides
// under the 32-step FMA loop instead of serializing barrier->load->barrier).
#define K1_BM 16
__global__ __launch_bounds__(256) void k1_gemm(const float* __restrict__ x,
                                               const float* __restrict__ W,
                                               float* __restrict__ Wh,
                                               unsigned short* __restrict__ WhT) {
    __shared__ float xsT[32][20];   // [k][r]
    const int t = threadIdx.x;      // = output column
    const int r0 = blockIdx.x * K1_BM;
    float acc[K1_BM];
#pragma unroll
    for (int i = 0; i < K1_BM; ++i) acc[i] = 0.f;

    const int lr = t >> 3, lks = (t & 7) * 4;   // loader coords (t < 128)
    float4 xv;
    if (t < 128) xv = *(const float4*)(x + (size_t)(r0 + lr) * D + lks);

    for (int k0 = 0; k0 < D; k0 += 32) {
        __syncthreads();
        if (t < 128) {
            xsT[lks + 0][lr] = xv.x; xsT[lks + 1][lr] = xv.y;
            xsT[lks + 2][lr] = xv.z; xsT[lks + 3][lr] = xv.w;
        }
        __syncthreads();
        if (t < 128 && k0 + 32 < D)   // prefetch next K-tile; consumed next iter
            xv = *(const float4*)(x + (size_t)(r0 + lr) * D + k0 + 32 + lks);
#pragma unroll 8
        for (int kk = 0; kk < 32; ++kk) {
            float wv = W[(size_t)(k0 + kk) * D + t];
#pragma unroll
            for (int rc = 0; rc < K1_BM / 4; ++rc) {
                float4 xr = *(const float4*)&xsT[kk][rc * 4];
                acc[rc * 4 + 0] += xr.x * wv;
                acc[rc * 4 + 1] += xr.y * wv;
                acc[rc * 4 + 2] += xr.z * wv;
                acc[rc * 4 + 3] += xr.w * wv;
            }
        }
    }
#pragma unroll
    for (int r = 0; r < K1_BM; ++r) Wh[(size_t)(r0 + r) * D + t] = acc[r];
    unsigned short pk[K1_BM];
#pragma unroll
    for (int r = 0; r < K1_BM; ++r) pk[r] = f2bf(acc[r]);
    uint4* dst = (uint4*)(WhT + (size_t)t * N + r0);
    dst[0] = *(uint4*)&pk[0];
    dst[1] = *(uint4*)&pk[8];
}

// ---------------- K2: e_src / e_dst (wave per row) ----------------
__global__ __launch_bounds__(256) void k2_edot(const float* __restrict__ Wh,
                                               const float* __restrict__ a,
                                               float* __restrict__ e_src,
                                               float* __restrict__ e_dst) {
    const int wave = threadIdx.x >> 6, lane = threadIdx.x & 63;
    const int row = blockIdx.x * 4 + wave;
    float4 wv = *(const float4*)(Wh + (size_t)row * D + lane * 4);
    float4 as = *(const float4*)(a + lane * 4);
    float4 ad = *(const float4*)(a + D + lane * 4);
    float ps = wv.x * as.x + wv.y * as.y + wv.z * as.z + wv.w * as.w;
    float pd = wv.x * ad.x + wv.y * ad.y + wv.z * ad.z + wv.w * ad.w;
#pragma unroll
    for (int m = 1; m < 64; m <<= 1) {
        ps += __shfl_xor(ps, m);
        pd += __shfl_xor(pd, m);
    }
    if (lane == 0) { e_src[row] = ps; e_dst[row] = pd; }
}

// ---------------- K3: maxdst = max(e_dst) ----------------
__global__ __launch_bounds__(256) void k3_max(const float* __restrict__ e_dst,
                                              float* __restrict__ maxdst) {
    __shared__ float red[4];
    const int t = threadIdx.x;
    float m = -3.4e38f;
    for (int i = t; i < N; i += 256) m = fmaxf(m, e_dst[i]);
#pragma unroll
    for (int msk = 1; msk < 64; msk <<= 1) m = fmaxf(m, __shfl_xor(m, msk));
    if ((t & 63) == 0) red[t >> 6] = m;
    __syncthreads();
    if (t == 0) *maxdst = fmaxf(fmaxf(red[0], red[1]), fmaxf(red[2], red[3]));
}

// ---------------- K4: masked softmax + PV matmul ----------------
// v2 changes vs prior best:
//  * adj (the 256 MB HBM stream) prefetched at DISTANCE 2 via ping-pong reg
//    buffers (A = even tiles, B = odd tiles): tile it+3 issued right after its
//    buffer is consumed -> 2x bytes-in-flight per wave (latency-bound fix).
//  * s = blockIdx & 7: round-robin dispatch pins each j-slice to one XCD so
//    its 512 KB WhT slice + e_dst slice stay L2-resident (bfr load latency).
//  * e_dst stays distance-1 (32 KB, L2-hot everywhere).
#define BM 64
#define BK 64
#define RB (N / BM)          // 128 row-blocks
#define SPLITS 8             // grid = RB*SPLITS = 1024
#define NITER ((N / SPLITS) / BK)   // 16
#define PSTRIDE 72           // ushorts per P row (144 B)
__global__ __launch_bounds__(512, 8) void k4_main(const float* __restrict__ adj,
                                                  const unsigned short* __restrict__ WhT,
                                                  const float* __restrict__ e_src,
                                                  const float* __restrict__ e_dst,
                                                  const float* __restrict__ maxdst,
                                                  float* __restrict__ O_part,
                                                  float* __restrict__ l_part) {
    __shared__ unsigned short p_lds[2][BM][PSTRIDE];   // double-buffered P tile, 18.4 KB

    const int t = threadIdx.x;
    const int rb = blockIdx.x >> 3;          // row-block
    const int s  = blockIdx.x & 7;           // j-slice == XCD (round-robin heuristic)
    const int r0 = rb * BM;
    const int j0 = s * (N / SPLITS);

    // P-generation coords: 8 threads per row, 8 cols each
    const int pr = t >> 3;            // 0..63
    const int pc = (t & 7) * 8;       // 0..56
    const int gr = r0 + pr;

    const int w = t >> 6;             // wave 0..7 -> output cols w*32..w*32+31
    const int lane = t & 63;
    const int quad = lane >> 4, lo = lane & 15;

    const float md = *maxdst;
    const float es = e_src[gr];
    const float m = leaky(es + md);

    f32x4 acc[4][2];
#pragma unroll
    for (int mt = 0; mt < 4; ++mt)
#pragma unroll
        for (int nt = 0; nt < 2; ++nt)
            acc[mt][nt] = (f32x4){0.f, 0.f, 0.f, 0.f};
    float lsum = 0.f;

    const float* adj_row = adj + (size_t)gr * N + j0 + pc;
    const float* ed_row  = e_dst + j0 + pc;
    // B-fragment base: row (= Wh col) = w*32 + nt*16 + lo, k offset = quad*8
    const unsigned short* wt_base = WhT + (size_t)(w * 32 + lo) * N + j0 + quad * 8;

    float4 aA0, aA1;                  // adj buffer A: even tiles
    float4 aB0, aB1;                  // adj buffer B: odd tiles
    float4 edv0, edv1;                // e_dst, distance-1
    bf16x8 bfr[2][2];                 // [ks2][nt], reissued after last use

    auto mma = [&](int cb) {
#pragma unroll
        for (int ks2 = 0; ks2 < 2; ++ks2) {
            bf16x8 afr[4];
#pragma unroll
            for (int mt = 0; mt < 4; ++mt)
                afr[mt] = *(const bf16x8*)&p_lds[cb][mt * 16 + lo][ks2 * 32 + quad * 8];
#pragma unroll
            for (int nt = 0; nt < 2; ++nt)
#pragma unroll
                for (int mt = 0; mt < 4; ++mt)
                    acc[mt][nt] = __builtin_amdgcn_mfma_f32_16x16x32_bf16(
                        afr[mt], bfr[ks2][nt], acc[mt][nt], 0, 0, 0);
        }
    };
    auto bfr_load = [&](int it) {
#pragma unroll
        for (int ks2 = 0; ks2 < 2; ++ks2)
#pragma unroll
            for (int nt = 0; nt < 2; ++nt)
                bfr[ks2][nt] = *(const bf16x8*)(wt_base + (size_t)nt * (16 * N) +
                                                it * BK + ks2 * 32);
    };
    // stage: P for tile `its` from the given regs -> p_lds[buf]; accumulates lsum
    auto stage = [&](int its, int buf, float4 a0, float4 a1, float4 e0, float4 e1) {
        const int jb = j0 + its * BK + pc;
        float av[8] = {a0.x, a0.y, a0.z, a0.w, a1.x, a1.y, a1.z, a1.w};
        float ev[8] = {e0.x, e0.y, e0.z, e0.w, e1.x, e1.y, e1.z, e1.w};
        unsigned short pk[8];
#pragma unroll
        for (int jj = 0; jj < 8; ++jj) {
            float e = leaky(es + ev[jj]);
            bool keep = (av[jj] > 0.f) || (jb + jj == gr);
            float p = keep ? __expf(e - m) : 0.f;
            lsum += p;
            pk[jj] = f2bf(p);
        }
        *(uint4*)&p_lds[buf][pr][pc] = *(uint4*)pk;
    };

    // ---- prologue: tiles 0(A), 1(B) issued; stage(0); tile 2 -> A ----
    aA0 = *(const float4*)(adj_row);
    aA1 = *(const float4*)(adj_row + 4);
    aB0 = *(const float4*)(adj_row + BK);
    aB1 = *(const float4*)(adj_row + BK + 4);
    edv0 = *(const float4*)(ed_row);
    edv1 = *(const float4*)(ed_row + 4);
    bfr_load(0);
    stage(0, 0, aA0, aA1, edv0, edv1);
    edv0 = *(const float4*)(ed_row + BK);              // ed tile 1
    edv1 = *(const float4*)(ed_row + BK + 4);
    aA0 = *(const float4*)(adj_row + 2 * BK);          // adj tile 2 -> A
    aA1 = *(const float4*)(adj_row + 2 * BK + 4);
    sync_lds();

    for (int it2 = 0; it2 < NITER / 2; ++it2) {
        // ======== even body: it = 2*it2, cb = 0 ========
        {
            const int it = it2 * 2;
            mma(0);
            bfr_load(it + 1);
            stage(it + 1, 1, aB0, aB1, edv0, edv1);    // consume B (odd tile)
            const int itn = (it + 2 < NITER) ? it + 2 : NITER - 1;
            edv0 = *(const float4*)(ed_row + itn * BK);
            edv1 = *(const float4*)(ed_row + itn * BK + 4);
            const int itn3 = (it + 3 < NITER) ? it + 3 : NITER - 1;
            aB0 = *(const float4*)(adj_row + itn3 * BK);       // refill B
            aB1 = *(const float4*)(adj_row + itn3 * BK + 4);
            sync_lds();
        }
        // ======== odd body: it = 2*it2+1, cb = 1 ========
        {
            const int it = it2 * 2 + 1;
            mma(1);
            const int itb = (it + 1 < NITER) ? it + 1 : NITER - 1;
            bfr_load(itb);
            if (it + 1 < NITER) {
                stage(it + 1, 0, aA0, aA1, edv0, edv1);        // consume A (even tile)
                const int itn = (it + 2 < NITER) ? it + 2 : NITER - 1;
                edv0 = *(const float4*)(ed_row + itn * BK);
                edv1 = *(const float4*)(ed_row + itn * BK + 4);
                const int itn3 = (it + 3 < NITER) ? it + 3 : NITER - 1;
                aA0 = *(const float4*)(adj_row + itn3 * BK);   // refill A
                aA1 = *(const float4*)(adj_row + itn3 * BK + 4);
            }
            sync_lds();
        }
    }

    // ---- epilogue: reduce per-row partial l (8 threads per row), write partials ----
#pragma unroll
    for (int msk = 1; msk < 8; msk <<= 1) lsum += __shfl_xor(lsum, msk);
    if ((t & 7) == 0) l_part[(size_t)s * N + gr] = lsum;

#pragma unroll
    for (int mt = 0; mt < 4; ++mt) {
#pragma unroll
        for (int nt = 0; nt < 2; ++nt) {
            f32x4 v = acc[mt][nt];
            int col = w * 32 + nt * 16 + lo;
#pragma unroll
            for (int reg = 0; reg < 4; ++reg) {
                int row = mt * 16 + quad * 4 + reg;
                O_part[((size_t)s * N + r0 + row) * D + col] = v[reg];
            }
        }
    }
}

// ---------------- K5: reduce partials (float4), divide by l ----------------
__global__ __launch_bounds__(256) void k5_reduce(const float* __restrict__ O_part,
                                                 const float* __restrict__ l_part,
                                                 float* __restrict__ out) {
    const int idx = blockIdx.x * 256 + threadIdx.x;   // over N*D/4
    const int r = idx >> 6;                           // D/4 = 64 float4 per row
    float lsum = 0.f;
#pragma unroll
    for (int s = 0; s < SPLITS; ++s) lsum += l_part[(size_t)s * N + r];
    f32x4 o = (f32x4){0.f, 0.f, 0.f, 0.f};
#pragma unroll
    for (int s = 0; s < SPLITS; ++s)
        o += *(const f32x4*)(O_part + (size_t)s * N * D + (size_t)idx * 4);
    const float inv = 1.f / lsum;
    *(f32x4*)(out + (size_t)idx * 4) = o * inv;
}

// ---------------- launch ----------------
extern "C" void kernel_launch(void* const* d_in, const int* in_sizes, int n_in,
                              void* d_out, int out_size, void* d_ws, size_t ws_size,
                              hipStream_t stream) {
    const float* x   = (const float*)d_in[0];   // [N, D]
    const float* adj = (const float*)d_in[1];   // [N, N]
    const float* W   = (const float*)d_in[2];   // [D, D]
    const float* a   = (const float*)d_in[3];   // [2*D]
    float* out = (float*)d_out;

    // ws layout (~80.1 MB):
    char* ws = (char*)d_ws;
    float* Wh            = (float*)(ws);                         // 8 MB
    unsigned short* WhT  = (unsigned short*)(ws + 8388608);      // 4 MB
    float* e_src         = (float*)(ws + 12582912);              // 32 KB
    float* e_dst         = (float*)(ws + 12615680);              // 32 KB
    float* maxdst        = (float*)(ws + 12648448);              // 256 B
    float* l_part        = (float*)(ws + 12648704);              // 256 KB (SPLITS*N*4)
    float* O_part        = (float*)(ws + 16777216);              // 64 MB (SPLITS*N*D*4)

    k1_gemm<<<N / K1_BM, 256, 0, stream>>>(x, W, Wh, WhT);
    k2_edot<<<N / 4, 256, 0, stream>>>(Wh, a, e_src, e_dst);
    k3_max<<<1, 256, 0, stream>>>(e_dst, maxdst);
    k4_main<<<RB * SPLITS, 512, 0, stream>>>(adj, WhT, e_src, e_dst, maxdst, O_part, l_part);
    k5_reduce<<<N * D / 4 / 256, 256, 0, stream>>>(O_part, l_part, out);
}

// Round 2
// 457.071 us; speedup vs baseline: 2.2297x; 2.2297x over previous
//
#include <hip/hip_runtime.h>
#include <stdint.h>

#define N 8192
#define D 256

typedef __attribute__((ext_vector_type(4))) float f32x4;
typedef __attribute__((ext_vector_type(8))) short bf16x8;

__device__ __forceinline__ unsigned short f2bf(float f) {
    unsigned u = __float_as_uint(f);
    u += 0x7fff + ((u >> 16) & 1);           // RNE
    return (unsigned short)(u >> 16);
}
__device__ __forceinline__ float leaky(float x) {
    return fmaxf(x, 0.f) + 0.2f * fminf(x, 0.f);
}
// CK-style block_sync_lds: LDS-ordering barrier that does NOT drain vmcnt,
// so register-destination global prefetches stay in flight across it.
__device__ __forceinline__ void sync_lds() {
    asm volatile("s_waitcnt lgkmcnt(0)\n\ts_barrier" ::: "memory");
}

// ---------------- K1: Wh = x @ W (fp32), also write WhT bf16 [D][N] ----------------
#define K1_BM 16
__global__ __launch_bounds__(256) void k1_gemm(const float* __restrict__ x,
                                               const float* __restrict__ W,
                                               float* __restrict__ Wh,
                                               unsigned short* __restrict__ WhT) {
    __shared__ float xsT[32][20];   // [k][r]
    const int t = threadIdx.x;      // = output column
    const int r0 = blockIdx.x * K1_BM;
    float acc[K1_BM];
#pragma unroll
    for (int i = 0; i < K1_BM; ++i) acc[i] = 0.f;

    const int lr = t >> 3, lks = (t & 7) * 4;   // loader coords (t < 128)
    float4 xv;
    if (t < 128) xv = *(const float4*)(x + (size_t)(r0 + lr) * D + lks);

    for (int k0 = 0; k0 < D; k0 += 32) {
        __syncthreads();
        if (t < 128) {
            xsT[lks + 0][lr] = xv.x; xsT[lks + 1][lr] = xv.y;
            xsT[lks + 2][lr] = xv.z; xsT[lks + 3][lr] = xv.w;
        }
        __syncthreads();
        if (t < 128 && k0 + 32 < D)   // prefetch next K-tile; consumed next iter
            xv = *(const float4*)(x + (size_t)(r0 + lr) * D + k0 + 32 + lks);
#pragma unroll 8
        for (int kk = 0; kk < 32; ++kk) {
            float wv = W[(size_t)(k0 + kk) * D + t];
#pragma unroll
            for (int rc = 0; rc < K1_BM / 4; ++rc) {
                float4 xr = *(const float4*)&xsT[kk][rc * 4];
                acc[rc * 4 + 0] += xr.x * wv;
                acc[rc * 4 + 1] += xr.y * wv;
                acc[rc * 4 + 2] += xr.z * wv;
                acc[rc * 4 + 3] += xr.w * wv;
            }
        }
    }
#pragma unroll
    for (int r = 0; r < K1_BM; ++r) Wh[(size_t)(r0 + r) * D + t] = acc[r];
    unsigned short pk[K1_BM];
#pragma unroll
    for (int r = 0; r < K1_BM; ++r) pk[r] = f2bf(acc[r]);
    uint4* dst = (uint4*)(WhT + (size_t)t * N + r0);
    dst[0] = *(uint4*)&pk[0];
    dst[1] = *(uint4*)&pk[8];
}

// ---------------- K2: e_src / e_dst (wave per row) ----------------
__global__ __launch_bounds__(256) void k2_edot(const float* __restrict__ Wh,
                                               const float* __restrict__ a,
                                               float* __restrict__ e_src,
                                               float* __restrict__ e_dst) {
    const int wave = threadIdx.x >> 6, lane = threadIdx.x & 63;
    const int row = blockIdx.x * 4 + wave;
    float4 wv = *(const float4*)(Wh + (size_t)row * D + lane * 4);
    float4 as = *(const float4*)(a + lane * 4);
    float4 ad = *(const float4*)(a + D + lane * 4);
    float ps = wv.x * as.x + wv.y * as.y + wv.z * as.z + wv.w * as.w;
    float pd = wv.x * ad.x + wv.y * ad.y + wv.z * ad.z + wv.w * ad.w;
#pragma unroll
    for (int m = 1; m < 64; m <<= 1) {
        ps += __shfl_xor(ps, m);
        pd += __shfl_xor(pd, m);
    }
    if (lane == 0) { e_src[row] = ps; e_dst[row] = pd; }
}

// ---------------- K3: maxdst = max(e_dst) ----------------
__global__ __launch_bounds__(256) void k3_max(const float* __restrict__ e_dst,
                                              float* __restrict__ maxdst) {
    __shared__ float red[4];
    const int t = threadIdx.x;
    float m = -3.4e38f;
    for (int i = t; i < N; i += 256) m = fmaxf(m, e_dst[i]);
#pragma unroll
    for (int msk = 1; msk < 64; msk <<= 1) m = fmaxf(m, __shfl_xor(m, msk));
    if ((t & 63) == 0) red[t >> 6] = m;
    __syncthreads();
    if (t == 0) *maxdst = fmaxf(fmaxf(red[0], red[1]), fmaxf(red[2], red[3]));
}

// ---------------- K4: masked softmax + PV matmul ----------------
// v4: de-phase the lockstep (all 32 waves/CU were hitting the same pipe at the
// same time; every pipe <=21% busy while wall = 4x the overlapped floor):
//  * per-block j-tile ROTATION: block processes tiles (it+rot)&15. Sums over j
//    commute, so this is semantics-preserving. Co-resident blocks (blockIdx
//    +-256) get rot {0,5,10,15} -> VALU/LDS/HBM/barrier phases interleave.
//  * stage VALU moved BEFORE the ds_read+MFMA phase inside each iteration.
//  * s_setprio(1) around the MFMA cluster (de-phased waves give the CU
//    scheduler a role-split to arbitrate).
//  * keeps: distance-2 adj ping-pong, XCD-pinned j-slices, (512,4) bounds.
#define BM 64
#define BK 64
#define RB (N / BM)          // 128 row-blocks
#define SPLITS 8             // grid = RB*SPLITS = 1024
#define NITER ((N / SPLITS) / BK)   // 16
#define PSTRIDE 72           // ushorts per P row (144 B)
__global__ __launch_bounds__(512, 4) void k4_main(const float* __restrict__ adj,
                                                  const unsigned short* __restrict__ WhT,
                                                  const float* __restrict__ e_src,
                                                  const float* __restrict__ e_dst,
                                                  const float* __restrict__ maxdst,
                                                  float* __restrict__ O_part,
                                                  float* __restrict__ l_part) {
    __shared__ unsigned short p_lds[2][BM][PSTRIDE];   // double-buffered P tile, 18.4 KB

    const int t = threadIdx.x;
    const int rb = blockIdx.x >> 3;          // row-block
    const int s  = blockIdx.x & 7;           // j-slice == XCD (round-robin heuristic)
    const int r0 = rb * BM;
    const int j0 = s * (N / SPLITS);
    // de-phasing rotation: co-resident blocks (blockIdx +-256) differ
    const int rot = ((blockIdx.x >> 8) * 5) & (NITER - 1);

    // P-generation coords: 8 threads per row, 8 cols each
    const int pr = t >> 3;            // 0..63
    const int pc = (t & 7) * 8;       // 0..56
    const int gr = r0 + pr;

    const int w = t >> 6;             // wave 0..7 -> output cols w*32..w*32+31
    const int lane = t & 63;
    const int quad = lane >> 4, lo = lane & 15;

    const float md = *maxdst;
    const float es = e_src[gr];
    const float m = leaky(es + md);

    f32x4 acc[4][2];
#pragma unroll
    for (int mt = 0; mt < 4; ++mt)
#pragma unroll
        for (int nt = 0; nt < 2; ++nt)
            acc[mt][nt] = (f32x4){0.f, 0.f, 0.f, 0.f};
    float lsum = 0.f;

    const float* adj_row = adj + (size_t)gr * N + j0 + pc;
    const float* ed_row  = e_dst + j0 + pc;
    // B-fragment base: row (= Wh col) = w*32 + nt*16 + lo, k offset = quad*8
    const unsigned short* wt_base = WhT + (size_t)(w * 32 + lo) * N + j0 + quad * 8;

    // logical iteration i -> rotated tile index (clamped for tail prefetches)
    auto jtf = [&](int i) {
        int c = (i < NITER) ? i : NITER - 1;
        return (c + rot) & (NITER - 1);
    };

    float4 aA0, aA1;                  // adj buffer A: even logical tiles
    float4 aB0, aB1;                  // adj buffer B: odd logical tiles
    float4 edv0, edv1;                // e_dst, distance-1
    bf16x8 bfr[2][2];                 // [ks2][nt], reissued after last use

    auto mma = [&](int cb) {
        __builtin_amdgcn_s_setprio(1);
#pragma unroll
        for (int ks2 = 0; ks2 < 2; ++ks2) {
            bf16x8 afr[4];
#pragma unroll
            for (int mt = 0; mt < 4; ++mt)
                afr[mt] = *(const bf16x8*)&p_lds[cb][mt * 16 + lo][ks2 * 32 + quad * 8];
#pragma unroll
            for (int nt = 0; nt < 2; ++nt)
#pragma unroll
                for (int mt = 0; mt < 4; ++mt)
                    acc[mt][nt] = __builtin_amdgcn_mfma_f32_16x16x32_bf16(
                        afr[mt], bfr[ks2][nt], acc[mt][nt], 0, 0, 0);
        }
        __builtin_amdgcn_s_setprio(0);
    };
    auto bfr_load = [&](int tile) {
#pragma unroll
        for (int ks2 = 0; ks2 < 2; ++ks2)
#pragma unroll
            for (int nt = 0; nt < 2; ++nt)
                bfr[ks2][nt] = *(const bf16x8*)(wt_base + (size_t)nt * (16 * N) +
                                                tile * BK + ks2 * 32);
    };
    // stage: P for rotated tile `tile` from the given regs -> p_lds[buf]
    auto stage = [&](int tile, int buf, float4 a0, float4 a1, float4 e0, float4 e1) {
        const int jb = j0 + tile * BK + pc;
        float av[8] = {a0.x, a0.y, a0.z, a0.w, a1.x, a1.y, a1.z, a1.w};
        float ev[8] = {e0.x, e0.y, e0.z, e0.w, e1.x, e1.y, e1.z, e1.w};
        unsigned short pk[8];
#pragma unroll
        for (int jj = 0; jj < 8; ++jj) {
            float e = leaky(es + ev[jj]);
            bool keep = (av[jj] > 0.f) || (jb + jj == gr);
            float p = keep ? __expf(e - m) : 0.f;
            lsum += p;
            pk[jj] = f2bf(p);
        }
        *(uint4*)&p_lds[buf][pr][pc] = *(uint4*)pk;
    };

    // ---- prologue: logical tiles 0(A), 1(B); stage(0); tile 2 -> A ----
    {
        const int t0 = jtf(0), t1 = jtf(1), t2 = jtf(2);
        aA0 = *(const float4*)(adj_row + t0 * BK);
        aA1 = *(const float4*)(adj_row + t0 * BK + 4);
        aB0 = *(const float4*)(adj_row + t1 * BK);
        aB1 = *(const float4*)(adj_row + t1 * BK + 4);
        edv0 = *(const float4*)(ed_row + t0 * BK);
        edv1 = *(const float4*)(ed_row + t0 * BK + 4);
        bfr_load(t0);
        stage(t0, 0, aA0, aA1, edv0, edv1);
        edv0 = *(const float4*)(ed_row + t1 * BK);         // ed tile 1
        edv1 = *(const float4*)(ed_row + t1 * BK + 4);
        aA0 = *(const float4*)(adj_row + t2 * BK);         // adj tile 2 -> A
        aA1 = *(const float4*)(adj_row + t2 * BK + 4);
    }
    sync_lds();

    for (int it2 = 0; it2 < NITER / 2; ++it2) {
        // ======== even body: it = 2*it2, cb = 0 ========
        {
            const int it = it2 * 2;
            stage(jtf(it + 1), 1, aB0, aB1, edv0, edv1);   // consume B (odd tile)
            {   // prefetch issues early, before the MFMA phase
                const int tn = jtf(it + 2), tn3 = jtf(it + 3);
                edv0 = *(const float4*)(ed_row + tn * BK);
                edv1 = *(const float4*)(ed_row + tn * BK + 4);
                aB0 = *(const float4*)(adj_row + tn3 * BK);        // refill B
                aB1 = *(const float4*)(adj_row + tn3 * BK + 4);
            }
            mma(0);
            bfr_load(jtf(it + 1));
            sync_lds();
        }
        // ======== odd body: it = 2*it2+1, cb = 1 ========
        {
            const int it = it2 * 2 + 1;
            if (it + 1 < NITER) {
                stage(jtf(it + 1), 0, aA0, aA1, edv0, edv1);       // consume A (even tile)
                const int tn = jtf(it + 2), tn3 = jtf(it + 3);
                edv0 = *(const float4*)(ed_row + tn * BK);
                edv1 = *(const float4*)(ed_row + tn * BK + 4);
                aA0 = *(const float4*)(adj_row + tn3 * BK);        // refill A
                aA1 = *(const float4*)(adj_row + tn3 * BK + 4);
            }
            mma(1);
            bfr_load(jtf(it + 1));
            sync_lds();
        }
    }

    // ---- epilogue: reduce per-row partial l (8 threads per row), write partials ----
#pragma unroll
    for (int msk = 1; msk < 8; msk <<= 1) lsum += __shfl_xor(lsum, msk);
    if ((t & 7) == 0) l_part[(size_t)s * N + gr] = lsum;

#pragma unroll
    for (int mt = 0; mt < 4; ++mt) {
#pragma unroll
        for (int nt = 0; nt < 2; ++nt) {
            f32x4 v = acc[mt][nt];
            int col = w * 32 + nt * 16 + lo;
#pragma unroll
            for (int reg = 0; reg < 4; ++reg) {
                int row = mt * 16 + quad * 4 + reg;
                O_part[((size_t)s * N + r0 + row) * D + col] = v[reg];
            }
        }
    }
}

// ---------------- K5: reduce partials (float4), divide by l ----------------
__global__ __launch_bounds__(256) void k5_reduce(const float* __restrict__ O_part,
                                                 const float* __restrict__ l_part,
                                                 float* __restrict__ out) {
    const int idx = blockIdx.x * 256 + threadIdx.x;   // over N*D/4
    const int r = idx >> 6;                           // D/4 = 64 float4 per row
    float lsum = 0.f;
#pragma unroll
    for (int s = 0; s < SPLITS; ++s) lsum += l_part[(size_t)s * N + r];
    f32x4 o = (f32x4){0.f, 0.f, 0.f, 0.f};
#pragma unroll
    for (int s = 0; s < SPLITS; ++s)
        o += *(const f32x4*)(O_part + (size_t)s * N * D + (size_t)idx * 4);
    const float inv = 1.f / lsum;
    *(f32x4*)(out + (size_t)idx * 4) = o * inv;
}

// ---------------- launch ----------------
extern "C" void kernel_launch(void* const* d_in, const int* in_sizes, int n_in,
                              void* d_out, int out_size, void* d_ws, size_t ws_size,
                              hipStream_t stream) {
    const float* x   = (const float*)d_in[0];   // [N, D]
    const float* adj = (const float*)d_in[1];   // [N, N]
    const float* W   = (const float*)d_in[2];   // [D, D]
    const float* a   = (const float*)d_in[3];   // [2*D]
    float* out = (float*)d_out;

    // ws layout (~80.1 MB):
    char* ws = (char*)d_ws;
    float* Wh            = (float*)(ws);                         // 8 MB
    unsigned short* WhT  = (unsigned short*)(ws + 8388608);      // 4 MB
    float* e_src         = (float*)(ws + 12582912);              // 32 KB
    float* e_dst         = (float*)(ws + 12615680);              // 32 KB
    float* maxdst        = (float*)(ws + 12648448);              // 256 B
    float* l_part        = (float*)(ws + 12648704);              // 256 KB (SPLITS*N*4)
    float* O_part        = (float*)(ws + 16777216);              // 64 MB (SPLITS*N*D*4)

    k1_gemm<<<N / K1_BM, 256, 0, stream>>>(x, W, Wh, WhT);
    k2_edot<<<N / 4, 256, 0, stream>>>(Wh, a, e_src, e_dst);
    k3_max<<<1, 256, 0, stream>>>(e_dst, maxdst);
    k4_main<<<RB * SPLITS, 512, 0, stream>>>(adj, WhT, e_src, e_dst, maxdst, O_part, l_part);
    k5_reduce<<<N * D / 4 / 256, 256, 0, stream>>>(O_part, l_part, out);
}